// Round 1
// baseline (240.273 us; speedup 1.0000x reference)
//
#include <hip/hip_runtime.h>

#define N_NODES 100000
#define D 128          // feature dim
#define K 16           // neighbors
#define CATK 256       // concat dim (2*D)
#define MB 32          // nodes per block
#define PAD 8
#define LDSW (CATK + PAD)   // 264 elements -> 528 B row stride (16B aligned, conflict-spread)

typedef __attribute__((ext_vector_type(8))) short bf16x8;
typedef __attribute__((ext_vector_type(4))) float f32x4;

__device__ __forceinline__ float bflo(unsigned u) {
    union { unsigned u; float f; } v; v.u = u << 16; return v.f;
}
__device__ __forceinline__ float bfhi(unsigned u) {
    union { unsigned u; float f; } v; v.u = u & 0xffff0000u; return v.f;
}
__device__ __forceinline__ unsigned short f2bf(float f) {
    union { float f; unsigned u; } v; v.f = f;
    unsigned u = v.u;
    return (unsigned short)((u + 0x7fffu + ((u >> 16) & 1u)) >> 16);  // RNE
}

// feats f32 -> bf16 bits
__global__ void cvt_feats(const float* __restrict__ in, unsigned short* __restrict__ out, int n) {
    int i4 = (blockIdx.x * blockDim.x + threadIdx.x) * 4;
    if (i4 >= n) return;
    float4 v = *(const float4*)(in + i4);
    ushort4 o;
    o.x = f2bf(v.x); o.y = f2bf(v.y); o.z = f2bf(v.z); o.w = f2bf(v.w);
    *(ushort4*)(out + i4) = o;
}

// Ws [2,256,128] f32 -> Wt [2,128,256] bf16 (transposed: Wt[l][n][k] = Ws[l][k][n])
__global__ void cvt_w(const float* __restrict__ Ws, unsigned short* __restrict__ Wt) {
    int t = blockIdx.x * blockDim.x + threadIdx.x;
    if (t >= 2 * CATK * D) return;
    int l = t / (CATK * D);
    int r = t % (CATK * D);
    int n = r / CATK;
    int k = r % CATK;
    Wt[t] = f2bf(Ws[l * CATK * D + k * D + n]);
}

// One GraphSAGE layer, fused gather+mean+concat+GEMM(+bias)(+relu)
// h:   [N,128] bf16 bits
// idx: [N,16]
// Wt:  [128,256] bf16 bits (output-col major, K contiguous)
// bias:[128] f32
template <int FINAL>
__launch_bounds__(256)
__global__ void sage_layer(const unsigned short* __restrict__ h,
                           const int* __restrict__ idx,
                           const unsigned short* __restrict__ Wt,
                           const float* __restrict__ bias,
                           unsigned short* __restrict__ h_out,
                           float* __restrict__ z_out) {
    __shared__ __align__(16) unsigned short sCat[MB][LDSW];
    __shared__ int sIdx[MB][K];

    const int t = threadIdx.x;
    const int base = blockIdx.x * MB;
    const int lane = t & 63;
    const int wave = t >> 6;
    const int q = lane >> 4;     // quad within wave
    const int nlo = lane & 15;   // low lane index

    // ---- stage neighbor indices ----
    for (int i = t; i < MB * K; i += 256) {
        int m = i >> 4, k = i & 15;
        sIdx[m][k] = idx[(base + m) * K + k];
    }
    __syncthreads();

    // ---- gather + mean + concat into LDS (bf16) ----
    {
        const int m = t >> 3;            // node within tile: 0..31
        const int c = (t & 7) * 16;      // 16-column slice: 0..112
        const int node = base + m;

        // self part: straight bf16 copy, 32 B
        const uint4* sp = (const uint4*)(h + node * D + c);
        uint4 s0 = sp[0];
        uint4 s1 = sp[1];
        *(uint4*)&sCat[m][c] = s0;
        *(uint4*)&sCat[m][c + 8] = s1;

        // aggregate part: mean over K neighbors
        float acc[16];
#pragma unroll
        for (int i = 0; i < 16; ++i) acc[i] = 0.f;
#pragma unroll 4
        for (int k = 0; k < K; ++k) {
            const uint4* p = (const uint4*)(h + sIdx[m][k] * D + c);
            uint4 u0 = p[0];
            uint4 u1 = p[1];
            unsigned uu[8] = {u0.x, u0.y, u0.z, u0.w, u1.x, u1.y, u1.z, u1.w};
#pragma unroll
            for (int j = 0; j < 8; ++j) {
                acc[2 * j]     += bflo(uu[j]);
                acc[2 * j + 1] += bfhi(uu[j]);
            }
        }
        unsigned pk[8];
#pragma unroll
        for (int j = 0; j < 8; ++j) {
            unsigned short a = f2bf(acc[2 * j] * (1.f / 16.f));
            unsigned short b = f2bf(acc[2 * j + 1] * (1.f / 16.f));
            pk[j] = (unsigned)a | ((unsigned)b << 16);
        }
        *(uint4*)&sCat[m][D + c]     = make_uint4(pk[0], pk[1], pk[2], pk[3]);
        *(uint4*)&sCat[m][D + c + 8] = make_uint4(pk[4], pk[5], pk[6], pk[7]);
    }

    // ---- load B fragments for this wave's 32 output cols (kept in VGPRs) ----
    bf16x8 bfrag[2][8];
#pragma unroll
    for (int ct = 0; ct < 2; ++ct) {
        int n = wave * 32 + ct * 16 + nlo;
        const unsigned short* wp = Wt + n * CATK + q * 8;
#pragma unroll
        for (int ks = 0; ks < 8; ++ks)
            bfrag[ct][ks] = *(const bf16x8*)(wp + ks * 32);
    }

    __syncthreads();

    // ---- MFMA: [32 x 256] x [256 x 32(this wave)] ----
    f32x4 acc00 = {}, acc01 = {}, acc10 = {}, acc11 = {};
#pragma unroll
    for (int ks = 0; ks < 8; ++ks) {
        bf16x8 a0 = *(const bf16x8*)&sCat[nlo][ks * 32 + q * 8];
        bf16x8 a1 = *(const bf16x8*)&sCat[16 + nlo][ks * 32 + q * 8];
        acc00 = __builtin_amdgcn_mfma_f32_16x16x32_bf16(a0, bfrag[0][ks], acc00, 0, 0, 0);
        acc01 = __builtin_amdgcn_mfma_f32_16x16x32_bf16(a0, bfrag[1][ks], acc01, 0, 0, 0);
        acc10 = __builtin_amdgcn_mfma_f32_16x16x32_bf16(a1, bfrag[0][ks], acc10, 0, 0, 0);
        acc11 = __builtin_amdgcn_mfma_f32_16x16x32_bf16(a1, bfrag[1][ks], acc11, 0, 0, 0);
    }

    // ---- epilogue: bias (+relu->bf16 | f32 store) ----
    // D layout: col = lane&15 (within 16-col tile), row = q*4 + r
#pragma unroll
    for (int ct = 0; ct < 2; ++ct) {
        int col = wave * 32 + ct * 16 + nlo;
        float bv = bias[col];
        f32x4 v0 = (ct == 0) ? acc00 : acc01;
        f32x4 v1 = (ct == 0) ? acc10 : acc11;
#pragma unroll
        for (int r = 0; r < 4; ++r) {
            int row0 = q * 4 + r;
            int row1 = 16 + q * 4 + r;
            float x0 = v0[r] + bv;
            float x1 = v1[r] + bv;
            if (FINAL) {
                z_out[(base + row0) * D + col] = x0;
                z_out[(base + row1) * D + col] = x1;
            } else {
                h_out[(base + row0) * D + col] = f2bf(x0 > 0.f ? x0 : 0.f);
                h_out[(base + row1) * D + col] = f2bf(x1 > 0.f ? x1 : 0.f);
            }
        }
    }
}

extern "C" void kernel_launch(void* const* d_in, const int* in_sizes, int n_in,
                              void* d_out, int out_size, void* d_ws, size_t ws_size,
                              hipStream_t stream) {
    const float* feats = (const float*)d_in[0];
    const int* neigh   = (const int*)d_in[1];
    const float* Ws    = (const float*)d_in[2];
    const float* bs    = (const float*)d_in[3];
    float* out = (float*)d_out;

    char* ws = (char*)d_ws;
    unsigned short* feats_bf = (unsigned short*)(ws);                    // 25,600,000 B
    unsigned short* h1_bf    = (unsigned short*)(ws + 25600000);         // 25,600,000 B
    unsigned short* Wt       = (unsigned short*)(ws + 51200000);         // 131,072 B

    const int nfeat = N_NODES * D;  // 12.8M
    cvt_feats<<<(nfeat / 4 + 255) / 256, 256, 0, stream>>>(feats, feats_bf, nfeat);
    cvt_w<<<(2 * CATK * D + 255) / 256, 256, 0, stream>>>(Ws, Wt);

    sage_layer<0><<<N_NODES / MB, 256, 0, stream>>>(
        feats_bf, neigh, Wt, bs, h1_bf, nullptr);
    sage_layer<1><<<N_NODES / MB, 256, 0, stream>>>(
        h1_bf, neigh + N_NODES * K, Wt + CATK * D, bs + D, nullptr, out);
}

// Round 2
// 213.151 us; speedup vs baseline: 1.1272x; 1.1272x over previous
//
#include <hip/hip_runtime.h>

#define N_NODES 100000
#define D 128          // feature dim
#define K 16           // neighbors
#define CATK 256       // concat dim (2*D)
#define MB 32          // nodes per block
#define PAD 8
#define LDSW (CATK + PAD)   // 264 bf16 elems -> 528 B row stride
#define ZW 132              // z-staging row stride in floats (528 B)

typedef __attribute__((ext_vector_type(8))) short bf16x8;
typedef __attribute__((ext_vector_type(4))) float f32x4;
typedef __attribute__((ext_vector_type(2))) float f32x2;

__device__ __forceinline__ unsigned short f2bf(float f) {
    union { float f; unsigned u; } v; v.f = f;
    unsigned u = v.u;
    return (unsigned short)((u + 0x7fffu + ((u >> 16) & 1u)) >> 16);  // RNE
}

// pack 4 floats -> 4 fp8 e4m3 bytes
__device__ __forceinline__ unsigned pk4(float a, float b, float c, float d) {
    int w = __builtin_amdgcn_cvt_pk_fp8_f32(a, b, 0, false);
    w = __builtin_amdgcn_cvt_pk_fp8_f32(c, d, w, true);
    return (unsigned)w;
}

// decode 4 fp8 bytes, accumulate into acc[0..3]
__device__ __forceinline__ void dec4(unsigned w, float* acc) {
    f32x2 lo = __builtin_amdgcn_cvt_pk_f32_fp8((int)w, false);
    f32x2 hi = __builtin_amdgcn_cvt_pk_f32_fp8((int)w, true);
    acc[0] += lo.x; acc[1] += lo.y; acc[2] += hi.x; acc[3] += hi.y;
}

// feats f32 -> fp8 table; also Ws [2,256,128] f32 -> Wt [2,128,256] bf16 (transposed)
__global__ void cvt_all(const float* __restrict__ feats, const float* __restrict__ Ws,
                        unsigned* __restrict__ f8, unsigned short* __restrict__ Wt) {
    int tid = blockIdx.x * 256 + threadIdx.x;
    int i = tid * 16;
    if (i < N_NODES * D) {
        const float4* p = (const float4*)(feats + i);
        float4 v0 = p[0], v1 = p[1], v2 = p[2], v3 = p[3];
        uint4 o;
        o.x = pk4(v0.x, v0.y, v0.z, v0.w);
        o.y = pk4(v1.x, v1.y, v1.z, v1.w);
        o.z = pk4(v2.x, v2.y, v2.z, v2.w);
        o.w = pk4(v3.x, v3.y, v3.z, v3.w);
        *(uint4*)(f8 + i / 4) = o;
    }
    if (tid < 2 * CATK * D) {
        int l = tid / (CATK * D);
        int r = tid % (CATK * D);
        int n = r / CATK, k = r % CATK;
        Wt[tid] = f2bf(Ws[l * CATK * D + k * D + n]);
    }
}

// One GraphSAGE layer: gather(fp8)+mean+concat+GEMM(+bias)(+relu)
// LAYER==0: self from f32 feats; outputs h1 bf16 + h1 fp8
// LAYER==1: self from bf16 h1; outputs z f32
template <int LAYER>
__launch_bounds__(256)
__global__ void sage_layer(const float* __restrict__ self_f32,
                           const unsigned short* __restrict__ self_bf,
                           const unsigned char* __restrict__ g8,
                           const int* __restrict__ idx,
                           const unsigned short* __restrict__ Wt,
                           const float* __restrict__ bias,
                           unsigned short* __restrict__ h_out,
                           unsigned char* __restrict__ h8_out,
                           float* __restrict__ z_out) {
    __shared__ __align__(16) char smraw[MB * LDSW * 2];   // 16896 B, dual-purpose
    unsigned short (*cat)[LDSW] = (unsigned short (*)[LDSW])smraw;
    float (*zb)[ZW] = (float (*)[ZW])smraw;
    __shared__ int sIdx[MB][K];

    const int t = threadIdx.x;
    const int base = blockIdx.x * MB;
    const int lane = t & 63;
    const int wave = t >> 6;
    const int q = lane >> 4;
    const int nlo = lane & 15;

    // ---- stage neighbor indices (int4-vectorized) ----
    if (t < MB * K / 4)
        ((int4*)&sIdx[0][0])[t] = ((const int4*)(idx + base * K))[t];
    __syncthreads();

    // ---- gather(fp8) + mean + self + concat into LDS (bf16) ----
    {
        const int m = t >> 3;            // node in tile
        const int c = (t & 7) * 16;      // 16-element column slice
        const int node = base + m;

        // self part
        if (LAYER == 0) {
            const float4* sp = (const float4*)(self_f32 + (size_t)node * D + c);
            float sv[16];
            *(f32x4*)&sv[0]  = *(const f32x4*)&sp[0];
            *(f32x4*)&sv[4]  = *(const f32x4*)&sp[1];
            *(f32x4*)&sv[8]  = *(const f32x4*)&sp[2];
            *(f32x4*)&sv[12] = *(const f32x4*)&sp[3];
            unsigned w[8];
#pragma unroll
            for (int j = 0; j < 8; ++j)
                w[j] = (unsigned)f2bf(sv[2 * j]) | ((unsigned)f2bf(sv[2 * j + 1]) << 16);
            *(uint4*)&cat[m][c]     = make_uint4(w[0], w[1], w[2], w[3]);
            *(uint4*)&cat[m][c + 8] = make_uint4(w[4], w[5], w[6], w[7]);
        } else {
            const uint4* sp = (const uint4*)(self_bf + (size_t)node * D + c);
            *(uint4*)&cat[m][c]     = sp[0];
            *(uint4*)&cat[m][c + 8] = sp[1];
        }

        // neighbor mean from fp8 table (16 B = 16 elems per load)
        float acc[16];
#pragma unroll
        for (int i = 0; i < 16; ++i) acc[i] = 0.f;
#pragma unroll 4
        for (int k = 0; k < K; ++k) {
            uint4 u = *(const uint4*)(g8 + (size_t)sIdx[m][k] * D + c);
            dec4(u.x, acc + 0);
            dec4(u.y, acc + 4);
            dec4(u.z, acc + 8);
            dec4(u.w, acc + 12);
        }
        unsigned pk[8];
#pragma unroll
        for (int j = 0; j < 8; ++j) {
            unsigned short a = f2bf(acc[2 * j] * (1.f / 16.f));
            unsigned short b = f2bf(acc[2 * j + 1] * (1.f / 16.f));
            pk[j] = (unsigned)a | ((unsigned)b << 16);
        }
        *(uint4*)&cat[m][D + c]     = make_uint4(pk[0], pk[1], pk[2], pk[3]);
        *(uint4*)&cat[m][D + c + 8] = make_uint4(pk[4], pk[5], pk[6], pk[7]);
    }

    // ---- per-wave B fragments (32 output cols, K=256) in VGPRs ----
    bf16x8 bfrag[2][8];
#pragma unroll
    for (int ct = 0; ct < 2; ++ct) {
        int n = wave * 32 + ct * 16 + nlo;
        const unsigned short* wp = Wt + n * CATK + q * 8;
#pragma unroll
        for (int ks = 0; ks < 8; ++ks)
            bfrag[ct][ks] = *(const bf16x8*)(wp + ks * 32);
    }

    __syncthreads();

    // ---- MFMA: [32 x 256] x [256 x 32(this wave)] ----
    f32x4 acc00 = {}, acc01 = {}, acc10 = {}, acc11 = {};
#pragma unroll
    for (int ks = 0; ks < 8; ++ks) {
        bf16x8 a0 = *(const bf16x8*)&cat[nlo][ks * 32 + q * 8];
        bf16x8 a1 = *(const bf16x8*)&cat[16 + nlo][ks * 32 + q * 8];
        acc00 = __builtin_amdgcn_mfma_f32_16x16x32_bf16(a0, bfrag[0][ks], acc00, 0, 0, 0);
        acc01 = __builtin_amdgcn_mfma_f32_16x16x32_bf16(a0, bfrag[1][ks], acc01, 0, 0, 0);
        acc10 = __builtin_amdgcn_mfma_f32_16x16x32_bf16(a1, bfrag[0][ks], acc10, 0, 0, 0);
        acc11 = __builtin_amdgcn_mfma_f32_16x16x32_bf16(a1, bfrag[1][ks], acc11, 0, 0, 0);
    }

    // ---- stage z tile into LDS (reusing cat's memory), then vector stores ----
    __syncthreads();  // all A-fragment reads done; safe to overwrite
#pragma unroll
    for (int ct = 0; ct < 2; ++ct) {
        int col = wave * 32 + ct * 16 + nlo;
        float bv = bias[col];
        f32x4 v0 = (ct == 0) ? acc00 : acc01;
        f32x4 v1 = (ct == 0) ? acc10 : acc11;
#pragma unroll
        for (int r = 0; r < 4; ++r) {
            zb[q * 4 + r][col]      = v0[r] + bv;
            zb[16 + q * 4 + r][col] = v1[r] + bv;
        }
    }
    __syncthreads();
    {
        const int m = t >> 3;
        const int c = (t & 7) * 16;
        float x[16];
        *(f32x4*)&x[0]  = *(const f32x4*)&zb[m][c];
        *(f32x4*)&x[4]  = *(const f32x4*)&zb[m][c + 4];
        *(f32x4*)&x[8]  = *(const f32x4*)&zb[m][c + 8];
        *(f32x4*)&x[12] = *(const f32x4*)&zb[m][c + 12];
        size_t go = (size_t)(base + m) * D + c;
        if (LAYER == 1) {
            float4* zp = (float4*)(z_out + go);
            zp[0] = make_float4(x[0], x[1], x[2], x[3]);
            zp[1] = make_float4(x[4], x[5], x[6], x[7]);
            zp[2] = make_float4(x[8], x[9], x[10], x[11]);
            zp[3] = make_float4(x[12], x[13], x[14], x[15]);
        } else {
#pragma unroll
            for (int i = 0; i < 16; ++i) x[i] = x[i] > 0.f ? x[i] : 0.f;
            unsigned wb[8];
#pragma unroll
            for (int j = 0; j < 8; ++j)
                wb[j] = (unsigned)f2bf(x[2 * j]) | ((unsigned)f2bf(x[2 * j + 1]) << 16);
            uint4* hp = (uint4*)(h_out + go);
            hp[0] = make_uint4(wb[0], wb[1], wb[2], wb[3]);
            hp[1] = make_uint4(wb[4], wb[5], wb[6], wb[7]);
            uint4 o8;
            o8.x = pk4(x[0], x[1], x[2], x[3]);
            o8.y = pk4(x[4], x[5], x[6], x[7]);
            o8.z = pk4(x[8], x[9], x[10], x[11]);
            o8.w = pk4(x[12], x[13], x[14], x[15]);
            *(uint4*)(h8_out + go) = o8;
        }
    }
}

extern "C" void kernel_launch(void* const* d_in, const int* in_sizes, int n_in,
                              void* d_out, int out_size, void* d_ws, size_t ws_size,
                              hipStream_t stream) {
    const float* feats = (const float*)d_in[0];
    const int* neigh   = (const int*)d_in[1];
    const float* Ws    = (const float*)d_in[2];
    const float* bs    = (const float*)d_in[3];
    float* out = (float*)d_out;

    char* ws = (char*)d_ws;
    unsigned short* h1_bf  = (unsigned short*)(ws);                 // 25,600,000 B
    unsigned char*  feats8 = (unsigned char*)(ws + 25600000);       // 12,800,000 B
    unsigned char*  h18    = (unsigned char*)(ws + 38400000);       // 12,800,000 B
    unsigned short* Wt     = (unsigned short*)(ws + 51200000);      //    131,072 B

    cvt_all<<<3125, 256, 0, stream>>>(feats, Ws, (unsigned*)feats8, Wt);

    sage_layer<0><<<N_NODES / MB, 256, 0, stream>>>(
        feats, nullptr, feats8, neigh, Wt, bs, h1_bf, h18, nullptr);
    sage_layer<1><<<N_NODES / MB, 256, 0, stream>>>(
        nullptr, h1_bf, h18, neigh + N_NODES * K, Wt + CATK * D, bs + D,
        nullptr, nullptr, out);
}